// Round 1
// baseline (5928.702 us; speedup 1.0000x reference)
//
#include <hip/hip_runtime.h>
#include <hip/hip_bf16.h>

// Problem: B=4, N=2048, DIMX=384, DIMQ=48, H=8.
// Restructure: M_h = W_rh * W_vh (384x384 per h);  U_bh = X_b * M_h^T;
//              out_b = sum_h softmax(Q_bh K_bh^T / sqrt(48)) * U_bh
// ws layout (bytes):
//   Mall  fp32 [8*384][384]                 @ 0        (4,718,592)
//   Qw    bf16 [(b*8+h)*2048 + i][48]       @ 4718592  (6,291,456)
//   Kw    bf16 same                          @ 11010048 (6,291,456)
//   Uw    bf16 [(b*8+h)*2048 + j][384]      @ 17301504 (50,331,648)
// total ~67.6 MB

// ---------- M_h = W_rh * W_vh ----------
// Mall[(h*384+d)*384+k] = sum_dx Wr[d*3072 + h*384+dx] * Wv[(h*384+dx)*384 + k]
__global__ __launch_bounds__(256) void prep_m_kernel(const float* __restrict__ Wr,
                                                     const float* __restrict__ Wv,
                                                     float* __restrict__ Mall) {
  __shared__ float As[32][68];  // [dx][d]
  __shared__ float Bs[32][68];  // [dx][k]
  const int t = threadIdx.x;
  const int d0 = blockIdx.x << 6;
  const int k0 = blockIdx.y << 6;
  const int h  = blockIdx.z;
  const int ty = t >> 4, tx = t & 15;
  float acc[4][4] = {};
  for (int x0 = 0; x0 < 384; x0 += 32) {
#pragma unroll
    for (int rep = 0; rep < 2; ++rep) {
      int idx = t + (rep << 8);
      int row = idx >> 3, kq = (idx & 7) << 2;  // A tile: 64 d-rows x 32 dx
      const float4 a = *(const float4*)&Wr[(size_t)(d0 + row) * 3072 + h * 384 + x0 + kq];
      As[kq + 0][row] = a.x; As[kq + 1][row] = a.y; As[kq + 2][row] = a.z; As[kq + 3][row] = a.w;
      int bro = idx >> 4, bc4 = (idx & 15) << 2; // B tile: 32 dx-rows x 64 k (already [dx][k])
      *(float4*)&Bs[bro][bc4] = *(const float4*)&Wv[(size_t)(h * 384 + x0 + bro) * 384 + k0 + bc4];
    }
    __syncthreads();
#pragma unroll
    for (int kk = 0; kk < 32; ++kk) {
      const float4 av = *(const float4*)&As[kk][ty << 2];
      const float4 bv = *(const float4*)&Bs[kk][tx << 2];
      const float a[4] = {av.x, av.y, av.z, av.w};
      const float b[4] = {bv.x, bv.y, bv.z, bv.w};
#pragma unroll
      for (int r = 0; r < 4; ++r)
#pragma unroll
        for (int c = 0; c < 4; ++c) acc[r][c] = fmaf(a[r], b[c], acc[r][c]);
    }
    __syncthreads();
  }
#pragma unroll
  for (int r = 0; r < 4; ++r)
#pragma unroll
    for (int c = 0; c < 4; ++c)
      Mall[(size_t)(h * 384 + d0 + (ty << 2) + r) * 384 + k0 + (tx << 2) + c] = acc[r][c];
}

// ---------- projection: P[m][n] = sum_k X[m*384+k]*W[n*384+k], store bf16 ----------
// DCHUNK=48: Q/K layout [(b*8+h)*2048+i][48]; DCHUNK=384: U layout [(b*8+h)*2048+i][384]
template <int DCHUNK>
__global__ __launch_bounds__(256) void proj_kernel(const float* __restrict__ X,
                                                   const float* __restrict__ W,
                                                   __hip_bfloat16* __restrict__ dst) {
  __shared__ float As[32][68];
  __shared__ float Bs[32][68];
  const int t = threadIdx.x;
  const int m0 = blockIdx.x << 6;
  const int n0 = blockIdx.y << 6;
  const int ty = t >> 4, tx = t & 15;
  float acc[4][4] = {};
  for (int k0 = 0; k0 < 384; k0 += 32) {
#pragma unroll
    for (int rep = 0; rep < 2; ++rep) {
      int idx = t + (rep << 8);
      int row = idx >> 3, kq = (idx & 7) << 2;
      const float4 a = *(const float4*)&X[(size_t)(m0 + row) * 384 + k0 + kq];
      As[kq + 0][row] = a.x; As[kq + 1][row] = a.y; As[kq + 2][row] = a.z; As[kq + 3][row] = a.w;
      const float4 b = *(const float4*)&W[(size_t)(n0 + row) * 384 + k0 + kq];
      Bs[kq + 0][row] = b.x; Bs[kq + 1][row] = b.y; Bs[kq + 2][row] = b.z; Bs[kq + 3][row] = b.w;
    }
    __syncthreads();
#pragma unroll
    for (int kk = 0; kk < 32; ++kk) {
      const float4 av = *(const float4*)&As[kk][ty << 2];
      const float4 bv = *(const float4*)&Bs[kk][tx << 2];
      const float a[4] = {av.x, av.y, av.z, av.w};
      const float b[4] = {bv.x, bv.y, bv.z, bv.w};
#pragma unroll
      for (int r = 0; r < 4; ++r)
#pragma unroll
        for (int c = 0; c < 4; ++c) acc[r][c] = fmaf(a[r], b[c], acc[r][c]);
    }
    __syncthreads();
  }
#pragma unroll
  for (int r = 0; r < 4; ++r)
#pragma unroll
    for (int c = 0; c < 4; ++c) {
      const int m = m0 + (ty << 2) + r;
      const int n = n0 + (tx << 2) + c;
      const int b = m >> 11, i = m & 2047;
      const int h = n / DCHUNK, dd = n % DCHUNK;
      dst[(size_t)(((b << 3) + h) * 2048 + i) * DCHUNK + dd] = __float2bfloat16(acc[r][c]);
    }
}

// ---------- fused attention: out += Z_bh * U_bh ----------
// grid (32 i-tiles, 4 b, 8 h), block 256. Unnormalized exp (safe: |s| small),
// row-sum l accumulated in regs, normalize at end, atomicAdd into zeroed out.
__global__ __launch_bounds__(256) void attn_pv_kernel(const __hip_bfloat16* __restrict__ Qw,
                                                      const __hip_bfloat16* __restrict__ Kw,
                                                      const __hip_bfloat16* __restrict__ Uw,
                                                      float* __restrict__ out) {
  __shared__ unsigned short Qs[64][52];
  __shared__ unsigned short Ks[64][52];
  __shared__ unsigned short Es[64][68];
  __shared__ unsigned short Us[32][384];
  __shared__ float Lrow[64];

  const int t  = threadIdx.x;
  const int i0 = blockIdx.x << 6;
  const int b  = blockIdx.y;
  const int h  = blockIdx.z;
  const int bh = (b << 3) + h;
  const unsigned short* Qg = (const unsigned short*)Qw + ((size_t)bh * 2048 + i0) * 48;
  const unsigned short* Kg = (const unsigned short*)Kw + (size_t)bh * 2048 * 48;
  const unsigned short* Ug = (const unsigned short*)Uw + (size_t)bh * 2048 * 384;

#pragma unroll
  for (int rep = 0; rep < 3; ++rep) {  // Q tile 64x48 = 768 ushort4
    int idx = t + (rep << 8);
    int row = idx / 12, c4 = (idx % 12) << 2;
    *(ushort4*)&Qs[row][c4] = *(const ushort4*)&Qg[row * 48 + c4];
  }

  const int zi  = t >> 2;        // score row  (z-phase)
  const int zjc = t & 3;         // score col sub
  const int pg  = t >> 4;        // PV: rows pg*4..+3
  const int pc  = (t & 15) * 24; // PV: cols pc..pc+23
  float acc[4][24] = {};
  float lpart = 0.f;
  const float scale = 0.14433756729740643f;  // 1/sqrt(48)

  for (int jt = 0; jt < 32; ++jt) {
    const int j0 = jt << 6;
    __syncthreads();  // prior users of Ks/Es/Us done
#pragma unroll
    for (int rep = 0; rep < 3; ++rep) {  // K tile 64x48
      int idx = t + (rep << 8);
      int row = idx / 12, c4 = (idx % 12) << 2;
      *(ushort4*)&Ks[row][c4] = *(const ushort4*)&Kg[(size_t)(j0 + row) * 48 + c4];
    }
    __syncthreads();
    // z-phase: 16 exp-scores per thread
#pragma unroll
    for (int jj = 0; jj < 16; ++jj) {
      const int j = (jj << 2) + zjc;
      float s = 0.f;
#pragma unroll
      for (int d = 0; d < 48; d += 2) {
        const unsigned int qp = *(const unsigned int*)&Qs[zi][d];
        const unsigned int kp = *(const unsigned int*)&Ks[j][d];
        s = fmaf(__uint_as_float(qp << 16), __uint_as_float(kp << 16), s);
        s = fmaf(__uint_as_float(qp & 0xffff0000u), __uint_as_float(kp & 0xffff0000u), s);
      }
      const float e = __expf(s * scale);
      lpart += e;
      __hip_bfloat16 eb = __float2bfloat16(e);
      Es[zi][j] = *reinterpret_cast<unsigned short*>(&eb);
    }
#pragma unroll
    for (int half = 0; half < 2; ++half) {
      __syncthreads();  // Es ready / previous PV done with Us
#pragma unroll
      for (int rep = 0; rep < 12; ++rep) {  // U half-tile 32x384 = 3072 ushort4
        int idx = t + (rep << 8);
        int row = idx / 96, c4 = (idx % 96) << 2;
        *(ushort4*)&Us[row][c4] = *(const ushort4*)&Ug[(size_t)(j0 + (half << 5) + row) * 384 + c4];
      }
      __syncthreads();
#pragma unroll
      for (int jj4 = 0; jj4 < 8; ++jj4) {
        const int jl = jj4 << 2;              // local j in half
        const int jg = (half << 5) + jl;      // j within tile (Es index)
        float z[4][4];
#pragma unroll
        for (int r = 0; r < 4; ++r) {
          const uint2 ez = *(const uint2*)&Es[(pg << 2) + r][jg];
          z[r][0] = __uint_as_float(ez.x << 16);
          z[r][1] = __uint_as_float(ez.x & 0xffff0000u);
          z[r][2] = __uint_as_float(ez.y << 16);
          z[r][3] = __uint_as_float(ez.y & 0xffff0000u);
        }
#pragma unroll
        for (int cc = 0; cc < 6; ++cc) {
          const int c = pc + (cc << 2);
#pragma unroll
          for (int jc = 0; jc < 4; ++jc) {
            const uint2 uu = *(const uint2*)&Us[jl + jc][c];
            const float u0 = __uint_as_float(uu.x << 16);
            const float u1 = __uint_as_float(uu.x & 0xffff0000u);
            const float u2 = __uint_as_float(uu.y << 16);
            const float u3 = __uint_as_float(uu.y & 0xffff0000u);
#pragma unroll
            for (int r = 0; r < 4; ++r) {
              acc[r][(cc << 2) + 0] = fmaf(z[r][jc], u0, acc[r][(cc << 2) + 0]);
              acc[r][(cc << 2) + 1] = fmaf(z[r][jc], u1, acc[r][(cc << 2) + 1]);
              acc[r][(cc << 2) + 2] = fmaf(z[r][jc], u2, acc[r][(cc << 2) + 2]);
              acc[r][(cc << 2) + 3] = fmaf(z[r][jc], u3, acc[r][(cc << 2) + 3]);
            }
          }
        }
      }
    }
  }
  // row-sum reduction: 4 lanes (zjc) per row
  float lsum = lpart;
  lsum += __shfl_xor(lsum, 1);
  lsum += __shfl_xor(lsum, 2);
  if (zjc == 0) Lrow[zi] = lsum;
  __syncthreads();
#pragma unroll
  for (int r = 0; r < 4; ++r) {
    const int i = (pg << 2) + r;
    const float inv = 1.0f / Lrow[i];
    float* op = &out[(size_t)((b * 2048) + i0 + i) * 384 + pc];
#pragma unroll
    for (int cc = 0; cc < 24; ++cc) atomicAdd(&op[cc], acc[r][cc] * inv);
  }
}

extern "C" void kernel_launch(void* const* d_in, const int* in_sizes, int n_in,
                              void* d_out, int out_size, void* d_ws, size_t ws_size,
                              hipStream_t stream) {
  const float* X  = (const float*)d_in[0];
  const float* Wq = (const float*)d_in[1];
  const float* Wk = (const float*)d_in[2];
  const float* Wv = (const float*)d_in[3];
  const float* Wr = (const float*)d_in[4];
  float* out = (float*)d_out;

  char* ws = (char*)d_ws;
  float* Mall          = (float*)(ws);
  __hip_bfloat16* Qw   = (__hip_bfloat16*)(ws + 4718592);
  __hip_bfloat16* Kw   = (__hip_bfloat16*)(ws + 4718592 + 6291456);
  __hip_bfloat16* Uw   = (__hip_bfloat16*)(ws + 4718592 + 2 * 6291456);

  hipMemsetAsync(d_out, 0, (size_t)3145728 * 4, stream);  // out accumulated via atomicAdd

  prep_m_kernel<<<dim3(6, 6, 8), 256, 0, stream>>>(Wr, Wv, Mall);
  proj_kernel<48><<<dim3(128, 6), 256, 0, stream>>>(X, Wq, Qw);
  proj_kernel<48><<<dim3(128, 6), 256, 0, stream>>>(X, Wk, Kw);
  proj_kernel<384><<<dim3(128, 48), 256, 0, stream>>>(X, Mall, Uw);
  attn_pv_kernel<<<dim3(32, 4, 8), 256, 0, stream>>>(Qw, Kw, Uw, out);
}

// Round 2
// 667.248 us; speedup vs baseline: 8.8853x; 8.8853x over previous
//
#include <hip/hip_runtime.h>
#include <hip/hip_bf16.h>

// B=4, N=2048, DIMX=384, DIMQ=48, H=8.
// out_b = sum_h softmax(Q K^T/sqrt(48)) @ U_bh,  U_bh = X_b M_h^T,  M_h = W_rh W_vh.
// ws layout (bytes):
//   Mall fp32 [8*384][384]              @ 0          (4,718,592)
//   Qw   bf16 [bh][i:2048][d:64 pad]    @ 4,718,592  (8,388,608)
//   Kw   bf16 same                      @ 13,107,200 (8,388,608)
//   UT   bf16 [bh][c:384][j:2048]       @ 21,495,808 (50,331,648)
//   Ow   bf16 [bh][i:2048][c:384]       @ 71,827,456 (50,331,648)  per-head partial O
// total 122,159,104 B

typedef short bf16x8 __attribute__((ext_vector_type(8)));
typedef float f32x4 __attribute__((ext_vector_type(4)));
typedef unsigned short ushort_t;
typedef unsigned int uint_t;

#define MFMA16(A, B, C) __builtin_amdgcn_mfma_f32_16x16x32_bf16(A, B, C, 0, 0, 0)

__device__ __forceinline__ uint_t pack_bf16(float a, float b) {
  __hip_bfloat16 ha = __float2bfloat16(a), hb = __float2bfloat16(b);
  return (uint_t)(*reinterpret_cast<ushort_t*>(&ha)) |
         ((uint_t)(*reinterpret_cast<ushort_t*>(&hb)) << 16);
}

// ---------- M_h = W_rh * W_vh ----------
__global__ __launch_bounds__(256) void prep_m_kernel(const float* __restrict__ Wr,
                                                     const float* __restrict__ Wv,
                                                     float* __restrict__ Mall) {
  __shared__ float As[32][68];
  __shared__ float Bs[32][68];
  const int t = threadIdx.x;
  const int d0 = blockIdx.x << 6;
  const int k0 = blockIdx.y << 6;
  const int h  = blockIdx.z;
  const int ty = t >> 4, tx = t & 15;
  float acc[4][4] = {};
  for (int x0 = 0; x0 < 384; x0 += 32) {
#pragma unroll
    for (int rep = 0; rep < 2; ++rep) {
      int idx = t + (rep << 8);
      int row = idx >> 3, kq = (idx & 7) << 2;
      const float4 a = *(const float4*)&Wr[(size_t)(d0 + row) * 3072 + h * 384 + x0 + kq];
      As[kq + 0][row] = a.x; As[kq + 1][row] = a.y; As[kq + 2][row] = a.z; As[kq + 3][row] = a.w;
      int bro = idx >> 4, bc4 = (idx & 15) << 2;
      *(float4*)&Bs[bro][bc4] = *(const float4*)&Wv[(size_t)(h * 384 + x0 + bro) * 384 + k0 + bc4];
    }
    __syncthreads();
#pragma unroll
    for (int kk = 0; kk < 32; ++kk) {
      const float4 av = *(const float4*)&As[kk][ty << 2];
      const float4 bv = *(const float4*)&Bs[kk][tx << 2];
      const float a[4] = {av.x, av.y, av.z, av.w};
      const float b[4] = {bv.x, bv.y, bv.z, bv.w};
#pragma unroll
      for (int r = 0; r < 4; ++r)
#pragma unroll
        for (int c = 0; c < 4; ++c) acc[r][c] = fmaf(a[r], b[c], acc[r][c]);
    }
    __syncthreads();
  }
#pragma unroll
  for (int r = 0; r < 4; ++r)
#pragma unroll
    for (int c = 0; c < 4; ++c)
      Mall[(size_t)(h * 384 + d0 + (ty << 2) + r) * 384 + k0 + (tx << 2) + c] = acc[r][c];
}

// ---------- projection: P[m][n] = sum_k X[m*384+k]*W[n*384+k] ----------
// MODE 0: Q/K -> dst[(bh*2048+i)*64 + dd] (dq padded to 64, pad pre-zeroed)
// MODE 1: U  -> dst[(bh*384+dd)*2048 + i] (transposed)
template <int MODE>
__global__ __launch_bounds__(256) void proj_kernel(const float* __restrict__ X,
                                                   const float* __restrict__ W,
                                                   __hip_bfloat16* __restrict__ dst) {
  __shared__ float As[32][68];
  __shared__ float Bs[32][68];
  const int t = threadIdx.x;
  const int m0 = blockIdx.x << 6;
  const int n0 = blockIdx.y << 6;
  const int ty = t >> 4, tx = t & 15;
  float acc[4][4] = {};
  for (int k0 = 0; k0 < 384; k0 += 32) {
#pragma unroll
    for (int rep = 0; rep < 2; ++rep) {
      int idx = t + (rep << 8);
      int row = idx >> 3, kq = (idx & 7) << 2;
      const float4 a = *(const float4*)&X[(size_t)(m0 + row) * 384 + k0 + kq];
      As[kq + 0][row] = a.x; As[kq + 1][row] = a.y; As[kq + 2][row] = a.z; As[kq + 3][row] = a.w;
      const float4 b = *(const float4*)&W[(size_t)(n0 + row) * 384 + k0 + kq];
      Bs[kq + 0][row] = b.x; Bs[kq + 1][row] = b.y; Bs[kq + 2][row] = b.z; Bs[kq + 3][row] = b.w;
    }
    __syncthreads();
#pragma unroll
    for (int kk = 0; kk < 32; ++kk) {
      const float4 av = *(const float4*)&As[kk][ty << 2];
      const float4 bv = *(const float4*)&Bs[kk][tx << 2];
      const float a[4] = {av.x, av.y, av.z, av.w};
      const float b[4] = {bv.x, bv.y, bv.z, bv.w};
#pragma unroll
      for (int r = 0; r < 4; ++r)
#pragma unroll
        for (int c = 0; c < 4; ++c) acc[r][c] = fmaf(a[r], b[c], acc[r][c]);
    }
    __syncthreads();
  }
#pragma unroll
  for (int r = 0; r < 4; ++r)
#pragma unroll
    for (int c = 0; c < 4; ++c) {
      const int m = m0 + (ty << 2) + r;
      const int n = n0 + (tx << 2) + c;
      const int b = m >> 11, i = m & 2047;
      if (MODE == 0) {
        const int h = n / 48, dd = n % 48;
        dst[(size_t)(((b << 3) + h) * 2048 + i) * 64 + dd] = __float2bfloat16(acc[r][c]);
      } else {
        const int h = n / 384, dd = n % 384;
        dst[((size_t)((b << 3) + h) * 384 + dd) * 2048 + i] = __float2bfloat16(acc[r][c]);
      }
    }
}

// ---------- fused attention via MFMA ----------
// grid flat 1024: h=bid&7 (XCD co-location per h), i0=((bid>>3)&31)*64, b=bid>>8.
// Per block: 64 queries x all 384 cols. j-tiles of 64.
// Scores: S^T = K Q^T via mfma (A=K rows, B=Q rows); exp -> LDS Ps[i][j] bf16;
// PV: A=P from LDS, B=UT 16B global frags; acc 4x6 f32x4 per lane.
__global__ __launch_bounds__(256, 2) void attn_pv_kernel(const ushort_t* __restrict__ Qw,
                                                         const ushort_t* __restrict__ Kw,
                                                         const ushort_t* __restrict__ UT,
                                                         __hip_bfloat16* __restrict__ Ow) {
  __shared__ uint_t Ps[64 * 36];  // [i][j-pair], stride 36 words (144B, 16B-aligned)
  __shared__ float Lw[4][64];
  __shared__ float Ls[64];

  const int t = threadIdx.x;
  const int w = t >> 6, lane = t & 63, quad = lane >> 4, l16 = lane & 15;
  const int bid = blockIdx.x;
  const int h = bid & 7, i0 = ((bid >> 3) & 31) << 6, b = bid >> 8;
  const int bh = (b << 3) + h;

  const ushort_t* Qg = Qw + ((size_t)bh * 2048 + i0 + l16) * 64 + quad * 8;
  const ushort_t* Kg = Kw + ((size_t)bh * 2048 + w * 16 + l16) * 64 + quad * 8;
  const ushort_t* Ug = UT + ((size_t)bh * 384 + w * 96 + l16) * 2048 + quad * 8;

  // Q B-fragments (resident all loop): B[k=d][n=i]
  bf16x8 qf[4][2];
#pragma unroll
  for (int ti = 0; ti < 4; ++ti)
#pragma unroll
    for (int kh = 0; kh < 2; ++kh)
      qf[ti][kh] = *(const bf16x8*)(Qg + (size_t)ti * 16 * 64 + kh * 32);

  f32x4 acc[4][6] = {};
  float lp[4] = {0.f, 0.f, 0.f, 0.f};
  const float scale = 0.14433756729740643f;  // 1/sqrt(48)

  bf16x8 kf0 = *(const bf16x8*)(Kg);
  bf16x8 kf1 = *(const bf16x8*)(Kg + 32);

  for (int jt = 0; jt < 32; ++jt) {
    const int j0 = jt << 6;
    // ---- scores: S^T tile, wave w owns j-strip w*16..+15 ----
    f32x4 sv[4];
#pragma unroll
    for (int ti = 0; ti < 4; ++ti) {
      f32x4 z = {0.f, 0.f, 0.f, 0.f};
      z = MFMA16(kf0, qf[ti][0], z);
      z = MFMA16(kf1, qf[ti][1], z);
      sv[ti] = z;
    }
    // prefetch next K tile while exp/barriers run
    const int jn = ((jt + 1) & 31) << 6;
    bf16x8 kn0 = *(const bf16x8*)(Kg + (size_t)jn * 64);
    bf16x8 kn1 = *(const bf16x8*)(Kg + (size_t)jn * 64 + 32);
    // ---- exp + pack (i = ti*16+l16, j = w*16+quad*4+r) ----
    uint_t pw[4][2];
#pragma unroll
    for (int ti = 0; ti < 4; ++ti) {
      const float e0 = __expf(sv[ti][0] * scale);
      const float e1 = __expf(sv[ti][1] * scale);
      const float e2 = __expf(sv[ti][2] * scale);
      const float e3 = __expf(sv[ti][3] * scale);
      lp[ti] += (e0 + e1) + (e2 + e3);
      pw[ti][0] = pack_bf16(e0, e1);
      pw[ti][1] = pack_bf16(e2, e3);
    }
    __syncthreads();  // previous PV done reading Ps
    {
      const int wbase = w * 8 + quad * 2;
#pragma unroll
      for (int ti = 0; ti < 4; ++ti) {
        uint_t* p = &Ps[(ti * 16 + l16) * 36 + wbase];
        p[0] = pw[ti][0];
        p[1] = pw[ti][1];
      }
    }
    __syncthreads();  // Ps ready
    // ---- P A-fragments from LDS: A[m=i=l16][k=j=ks*32+quad*8+e] ----
    bf16x8 pA[4][2];
#pragma unroll
    for (int ti = 0; ti < 4; ++ti)
#pragma unroll
      for (int ks = 0; ks < 2; ++ks)
        pA[ti][ks] = *(const bf16x8*)&Ps[(ti * 16 + l16) * 36 + ks * 16 + quad * 4];
    // ---- PV: B from UT (16B frags), wave owns c-range w*96..+95 ----
#pragma unroll
    for (int tc = 0; tc < 6; ++tc) {
      const ushort_t* up = Ug + (size_t)tc * 16 * 2048 + j0;
      const bf16x8 u0 = *(const bf16x8*)(up);
      const bf16x8 u1 = *(const bf16x8*)(up + 32);
#pragma unroll
      for (int ti = 0; ti < 4; ++ti) acc[ti][tc] = MFMA16(pA[ti][0], u0, acc[ti][tc]);
#pragma unroll
      for (int ti = 0; ti < 4; ++ti) acc[ti][tc] = MFMA16(pA[ti][1], u1, acc[ti][tc]);
    }
    kf0 = kn0;
    kf1 = kn1;
  }

  // ---- softmax denominators ----
#pragma unroll
  for (int ti = 0; ti < 4; ++ti) {
    lp[ti] += __shfl_xor(lp[ti], 16);
    lp[ti] += __shfl_xor(lp[ti], 32);
  }
  if (lane < 16) {
#pragma unroll
    for (int ti = 0; ti < 4; ++ti) Lw[w][ti * 16 + lane] = lp[ti];
  }
  __syncthreads();
  if (t < 64) Ls[t] = 1.0f / (Lw[0][t] + Lw[1][t] + Lw[2][t] + Lw[3][t]);
  __syncthreads();

  // ---- epilogue: normalize, store bf16 partial O ----
  __hip_bfloat16* Op = Ow + ((size_t)bh * 2048 + i0) * 384 + w * 96 + l16;
#pragma unroll
  for (int ti = 0; ti < 4; ++ti)
#pragma unroll
    for (int r = 0; r < 4; ++r) {
      const float inv = Ls[ti * 16 + quad * 4 + r];
      __hip_bfloat16* op = Op + (size_t)(ti * 16 + quad * 4 + r) * 384;
#pragma unroll
      for (int tc = 0; tc < 6; ++tc) op[tc * 16] = __float2bfloat16(acc[ti][tc][r] * inv);
    }
}

// ---------- reduce 8 heads: out[b][i][c] = sum_h Ow[bh][i][c] ----------
__global__ __launch_bounds__(256) void reduce_kernel(const uint_t* __restrict__ OwU,
                                                     float2* __restrict__ out) {
  const int idx = blockIdx.x * 256 + threadIdx.x;  // over 4*2048*192 uint pairs
  const int b = idx / 393216;
  const int rem = idx - b * 393216;
  const uint_t* p = OwU + (size_t)b * 8 * 393216 + rem;
  float s0 = 0.f, s1 = 0.f;
#pragma unroll
  for (int h = 0; h < 8; ++h) {
    const uint_t v = p[(size_t)h * 393216];
    s0 += __uint_as_float(v << 16);
    s1 += __uint_as_float(v & 0xffff0000u);
  }
  out[(size_t)b * 393216 + rem] = float2{s0, s1};
}

extern "C" void kernel_launch(void* const* d_in, const int* in_sizes, int n_in,
                              void* d_out, int out_size, void* d_ws, size_t ws_size,
                              hipStream_t stream) {
  const float* X  = (const float*)d_in[0];
  const float* Wq = (const float*)d_in[1];
  const float* Wk = (const float*)d_in[2];
  const float* Wv = (const float*)d_in[3];
  const float* Wr = (const float*)d_in[4];

  char* ws = (char*)d_ws;
  float* Mall        = (float*)(ws);
  __hip_bfloat16* Qw = (__hip_bfloat16*)(ws + 4718592);
  __hip_bfloat16* Kw = (__hip_bfloat16*)(ws + 13107200);
  __hip_bfloat16* UT = (__hip_bfloat16*)(ws + 21495808);
  __hip_bfloat16* Ow = (__hip_bfloat16*)(ws + 71827456);

  // zero the dq 48->64 pad of Q/K (contiguous 16 MB region)
  hipMemsetAsync(ws + 4718592, 0, 16777216, stream);

  prep_m_kernel<<<dim3(6, 6, 8), 256, 0, stream>>>(Wr, Wv, Mall);
  proj_kernel<0><<<dim3(128, 6), 256, 0, stream>>>(X, Wq, Qw);
  proj_kernel<0><<<dim3(128, 6), 256, 0, stream>>>(X, Wk, Kw);
  proj_kernel<1><<<dim3(128, 48), 256, 0, stream>>>(X, Mall, UT);
  attn_pv_kernel<<<dim3(1024), 256, 0, stream>>>((const ushort_t*)Qw, (const ushort_t*)Kw,
                                                 (const ushort_t*)UT, Ow);
  reduce_kernel<<<dim3(6144), 256, 0, stream>>>((const uint_t*)Ow, (float2*)d_out);
}

// Round 3
// 392.847 us; speedup vs baseline: 15.0916x; 1.6985x over previous
//
#include <hip/hip_runtime.h>
#include <hip/hip_bf16.h>

// B=4, N=2048, DIMX=384, DIMQ=48, H=8.
// out_b = sum_h softmax(Q K^T/sqrt(48)) @ U_bh,  U_bh = X_b M_h^T,  M_h = W_rh W_vh.
// ws layout (bytes), with Xw/Wqw/Wkw aliased INSIDE Ow (dead until attn runs):
//   Mw  bf16 [h*384+c][k:384]          @ 0           (2,359,296)
//   Qw  bf16 [bh][i:2048][d:64 pad]    @ 2,359,296   (8,388,608)
//   Kw  bf16 same                      @ 10,747,904  (8,388,608)
//   UT  bf16 [bh][c:384][j:2048]       @ 19,136,512  (50,331,648)
//   Ow  bf16 [bh][i:2048][c:384]       @ 69,468,160  (50,331,648)
//     Xw  bf16 [b][j:2048][k:384]      @ 69,468,160  (6,291,456)   } aliases Ow,
//     Wqw bf16 [384][384]              @ 75,759,616  (294,912)     } clobbered by attn
//     Wkw bf16 [384][384]              @ 76,054,528  (294,912)     } epilogue (safe: same stream)
// peak = 119,799,808 B  (< 122.2 MB round-2 footprint)

typedef short bf16x8 __attribute__((ext_vector_type(8)));
typedef float f32x4 __attribute__((ext_vector_type(4)));
typedef unsigned short ushort_t;
typedef unsigned int uint_t;

#define MFMA16(A, B, C) __builtin_amdgcn_mfma_f32_16x16x32_bf16(A, B, C, 0, 0, 0)

__device__ __forceinline__ ushort_t bits_bf16(float a) {
  __hip_bfloat16 h = __float2bfloat16(a);
  return *reinterpret_cast<ushort_t*>(&h);
}
__device__ __forceinline__ uint_t pack_bf16(float a, float b) {
  return (uint_t)bits_bf16(a) | ((uint_t)bits_bf16(b) << 16);
}

// ---------- fp32 -> bf16 convert ----------
__global__ __launch_bounds__(256) void cvt_kernel(const float* __restrict__ src,
                                                  ushort_t* __restrict__ dst, int n4) {
  const int idx = blockIdx.x * 256 + threadIdx.x;
  if (idx >= n4) return;
  const float4 v = ((const float4*)src)[idx];
  ushort4 o;
  o.x = bits_bf16(v.x); o.y = bits_bf16(v.y); o.z = bits_bf16(v.z); o.w = bits_bf16(v.w);
  ((ushort4*)dst)[idx] = o;
}

// ---------- M_h = W_rh * W_vh  (fp32 compute, bf16 out; tiny: 0.9 GF) ----------
__global__ __launch_bounds__(256) void prep_m_kernel(const float* __restrict__ Wr,
                                                     const float* __restrict__ Wv,
                                                     ushort_t* __restrict__ Mw) {
  __shared__ float As[32][68];
  __shared__ float Bs[32][68];
  const int t = threadIdx.x;
  const int d0 = blockIdx.x << 6;
  const int k0 = blockIdx.y << 6;
  const int h  = blockIdx.z;
  const int ty = t >> 4, tx = t & 15;
  float acc[4][4] = {};
  for (int x0 = 0; x0 < 384; x0 += 32) {
#pragma unroll
    for (int rep = 0; rep < 2; ++rep) {
      int idx = t + (rep << 8);
      int row = idx >> 3, kq = (idx & 7) << 2;
      const float4 a = *(const float4*)&Wr[(size_t)(d0 + row) * 3072 + h * 384 + x0 + kq];
      As[kq + 0][row] = a.x; As[kq + 1][row] = a.y; As[kq + 2][row] = a.z; As[kq + 3][row] = a.w;
      int bro = idx >> 4, bc4 = (idx & 15) << 2;
      *(float4*)&Bs[bro][bc4] = *(const float4*)&Wv[(size_t)(h * 384 + x0 + bro) * 384 + k0 + bc4];
    }
    __syncthreads();
#pragma unroll
    for (int kk = 0; kk < 32; ++kk) {
      const float4 av = *(const float4*)&As[kk][ty << 2];
      const float4 bv = *(const float4*)&Bs[kk][tx << 2];
      const float a[4] = {av.x, av.y, av.z, av.w};
      const float b[4] = {bv.x, bv.y, bv.z, bv.w};
#pragma unroll
      for (int r = 0; r < 4; ++r)
#pragma unroll
        for (int c = 0; c < 4; ++c) acc[r][c] = fmaf(a[r], b[c], acc[r][c]);
    }
    __syncthreads();
  }
#pragma unroll
  for (int r = 0; r < 4; ++r)
#pragma unroll
    for (int c = 0; c < 4; ++c)
      Mw[(size_t)(h * 384 + d0 + (ty << 2) + r) * 384 + k0 + (tx << 2) + c] =
          bits_bf16(acc[r][c]);
}

// ---------- unified bf16 MFMA GEMM: C[m][n] = sum_k A[m][k] * Bmat[n][k] ----------
// 128x128 block tile, 4 waves in 2x2, 64x64 per wave, K-step 32, 12 steps.
// MODE 0 (Q/K proj): A=Xw[8192][384], Bmat=W[384][384]; store Qw-style [(bh*2048+i)*64+dd]
// MODE 1 (U proj):   per bh (blockIdx.z): A=Mw_h[384][384], Bmat=Xw_b[2048][384];
//                    store UT[(bh*384+c)*2048+j]
template <int MODE>
__global__ __launch_bounds__(256) void gemm_kernel(const ushort_t* __restrict__ Aall,
                                                   const ushort_t* __restrict__ Ball,
                                                   ushort_t* __restrict__ dst) {
  __shared__ ushort_t As[128 * 40];  // row stride 40 (+8B pad: b128 reads 2-way max)
  __shared__ ushort_t Bs[128 * 40];
  const int t = threadIdx.x;
  const int w = t >> 6, lane = t & 63, quad = lane >> 4, l16 = lane & 15;
  const int m0 = blockIdx.x << 7;
  const int n0 = blockIdx.y << 7;
  const ushort_t* Ap;
  const ushort_t* Bp;
  if (MODE == 0) {
    Ap = Aall; Bp = Ball;
  } else {
    const int bh = blockIdx.z, h = bh & 7, b = bh >> 3;
    Ap = Aall + (size_t)h * 384 * 384;
    Bp = Ball + (size_t)b * 2048 * 384;
  }
  const int wm = (w & 1) << 6, wn = (w >> 1) << 6;
  f32x4 acc[4][4] = {};

  for (int k0 = 0; k0 < 384; k0 += 32) {
    __syncthreads();
#pragma unroll
    for (int rep = 0; rep < 2; ++rep) {
      const int idx = t + (rep << 8);
      const int row = idx >> 2, c8 = (idx & 3) << 3;
      *(bf16x8*)&As[row * 40 + c8] = *(const bf16x8*)&Ap[(size_t)(m0 + row) * 384 + k0 + c8];
      *(bf16x8*)&Bs[row * 40 + c8] = *(const bf16x8*)&Bp[(size_t)(n0 + row) * 384 + k0 + c8];
    }
    __syncthreads();
    bf16x8 af[4], bf[4];
#pragma unroll
    for (int x = 0; x < 4; ++x) {
      af[x] = *(const bf16x8*)&As[(wm + x * 16 + l16) * 40 + quad * 8];
      bf[x] = *(const bf16x8*)&Bs[(wn + x * 16 + l16) * 40 + quad * 8];
    }
#pragma unroll
    for (int ti = 0; ti < 4; ++ti)
#pragma unroll
      for (int tj = 0; tj < 4; ++tj)
        acc[ti][tj] = MFMA16(af[ti], bf[tj], acc[ti][tj]);
  }

#pragma unroll
  for (int ti = 0; ti < 4; ++ti) {
    const int gm0 = m0 + wm + ti * 16 + quad * 4;
#pragma unroll
    for (int tj = 0; tj < 4; ++tj) {
      const int gn = n0 + wn + tj * 16 + l16;
#pragma unroll
      for (int r = 0; r < 4; ++r) {
        const ushort_t v = bits_bf16(acc[ti][tj][r]);
        if (MODE == 0) {
          const int m = gm0 + r, b = m >> 11, i = m & 2047;
          const int h = gn / 48, dd = gn - h * 48;
          dst[(size_t)(((b << 3) + h) * 2048 + i) * 64 + dd] = v;
        } else {
          dst[((size_t)blockIdx.z * 384 + gm0 + r) * 2048 + gn] = v;
        }
      }
    }
  }
}

// ---------- fused attention via MFMA (unchanged from round 2) ----------
__global__ __launch_bounds__(256, 2) void attn_pv_kernel(const ushort_t* __restrict__ Qw,
                                                         const ushort_t* __restrict__ Kw,
                                                         const ushort_t* __restrict__ UT,
                                                         __hip_bfloat16* __restrict__ Ow) {
  __shared__ uint_t Ps[64 * 36];
  __shared__ float Lw[4][64];
  __shared__ float Ls[64];

  const int t = threadIdx.x;
  const int w = t >> 6, lane = t & 63, quad = lane >> 4, l16 = lane & 15;
  const int bid = blockIdx.x;
  const int h = bid & 7, i0 = ((bid >> 3) & 31) << 6, b = bid >> 8;
  const int bh = (b << 3) + h;

  const ushort_t* Qg = Qw + ((size_t)bh * 2048 + i0 + l16) * 64 + quad * 8;
  const ushort_t* Kg = Kw + ((size_t)bh * 2048 + w * 16 + l16) * 64 + quad * 8;
  const ushort_t* Ug = UT + ((size_t)bh * 384 + w * 96 + l16) * 2048 + quad * 8;

  bf16x8 qf[4][2];
#pragma unroll
  for (int ti = 0; ti < 4; ++ti)
#pragma unroll
    for (int kh = 0; kh < 2; ++kh)
      qf[ti][kh] = *(const bf16x8*)(Qg + (size_t)ti * 16 * 64 + kh * 32);

  f32x4 acc[4][6] = {};
  float lp[4] = {0.f, 0.f, 0.f, 0.f};
  const float scale = 0.14433756729740643f;  // 1/sqrt(48)

  bf16x8 kf0 = *(const bf16x8*)(Kg);
  bf16x8 kf1 = *(const bf16x8*)(Kg + 32);

  for (int jt = 0; jt < 32; ++jt) {
    const int j0 = jt << 6;
    f32x4 sv[4];
#pragma unroll
    for (int ti = 0; ti < 4; ++ti) {
      f32x4 z = {0.f, 0.f, 0.f, 0.f};
      z = MFMA16(kf0, qf[ti][0], z);
      z = MFMA16(kf1, qf[ti][1], z);
      sv[ti] = z;
    }
    const int jn = ((jt + 1) & 31) << 6;
    bf16x8 kn0 = *(const bf16x8*)(Kg + (size_t)jn * 64);
    bf16x8 kn1 = *(const bf16x8*)(Kg + (size_t)jn * 64 + 32);
    uint_t pw[4][2];
#pragma unroll
    for (int ti = 0; ti < 4; ++ti) {
      const float e0 = __expf(sv[ti][0] * scale);
      const float e1 = __expf(sv[ti][1] * scale);
      const float e2 = __expf(sv[ti][2] * scale);
      const float e3 = __expf(sv[ti][3] * scale);
      lp[ti] += (e0 + e1) + (e2 + e3);
      pw[ti][0] = pack_bf16(e0, e1);
      pw[ti][1] = pack_bf16(e2, e3);
    }
    __syncthreads();
    {
      const int wbase = w * 8 + quad * 2;
#pragma unroll
      for (int ti = 0; ti < 4; ++ti) {
        uint_t* p = &Ps[(ti * 16 + l16) * 36 + wbase];
        p[0] = pw[ti][0];
        p[1] = pw[ti][1];
      }
    }
    __syncthreads();
    bf16x8 pA[4][2];
#pragma unroll
    for (int ti = 0; ti < 4; ++ti)
#pragma unroll
      for (int ks = 0; ks < 2; ++ks)
        pA[ti][ks] = *(const bf16x8*)&Ps[(ti * 16 + l16) * 36 + ks * 16 + quad * 4];
#pragma unroll
    for (int tc = 0; tc < 6; ++tc) {
      const ushort_t* up = Ug + (size_t)tc * 16 * 2048 + j0;
      const bf16x8 u0 = *(const bf16x8*)(up);
      const bf16x8 u1 = *(const bf16x8*)(up + 32);
#pragma unroll
      for (int ti = 0; ti < 4; ++ti) acc[ti][tc] = MFMA16(pA[ti][0], u0, acc[ti][tc]);
#pragma unroll
      for (int ti = 0; ti < 4; ++ti) acc[ti][tc] = MFMA16(pA[ti][1], u1, acc[ti][tc]);
    }
    kf0 = kn0;
    kf1 = kn1;
  }

#pragma unroll
  for (int ti = 0; ti < 4; ++ti) {
    lp[ti] += __shfl_xor(lp[ti], 16);
    lp[ti] += __shfl_xor(lp[ti], 32);
  }
  if (lane < 16) {
#pragma unroll
    for (int ti = 0; ti < 4; ++ti) Lw[w][ti * 16 + lane] = lp[ti];
  }
  __syncthreads();
  if (t < 64) Ls[t] = 1.0f / (Lw[0][t] + Lw[1][t] + Lw[2][t] + Lw[3][t]);
  __syncthreads();

  __hip_bfloat16* Op = Ow + ((size_t)bh * 2048 + i0) * 384 + w * 96 + l16;
#pragma unroll
  for (int ti = 0; ti < 4; ++ti)
#pragma unroll
    for (int r = 0; r < 4; ++r) {
      const float inv = Ls[ti * 16 + quad * 4 + r];
      __hip_bfloat16* op = Op + (size_t)(ti * 16 + quad * 4 + r) * 384;
#pragma unroll
      for (int tc = 0; tc < 6; ++tc) op[tc * 16] = __float2bfloat16(acc[ti][tc][r] * inv);
    }
}

// ---------- reduce 8 heads ----------
__global__ __launch_bounds__(256) void reduce_kernel(const uint_t* __restrict__ OwU,
                                                     float2* __restrict__ out) {
  const int idx = blockIdx.x * 256 + threadIdx.x;
  const int b = idx / 393216;
  const int rem = idx - b * 393216;
  const uint_t* p = OwU + (size_t)b * 8 * 393216 + rem;
  float s0 = 0.f, s1 = 0.f;
#pragma unroll
  for (int h = 0; h < 8; ++h) {
    const uint_t v = p[(size_t)h * 393216];
    s0 += __uint_as_float(v << 16);
    s1 += __uint_as_float(v & 0xffff0000u);
  }
  out[(size_t)b * 393216 + rem] = float2{s0, s1};
}

extern "C" void kernel_launch(void* const* d_in, const int* in_sizes, int n_in,
                              void* d_out, int out_size, void* d_ws, size_t ws_size,
                              hipStream_t stream) {
  const float* X  = (const float*)d_in[0];
  const float* Wq = (const float*)d_in[1];
  const float* Wk = (const float*)d_in[2];
  const float* Wv = (const float*)d_in[3];
  const float* Wr = (const float*)d_in[4];

  char* ws = (char*)d_ws;
  ushort_t* Mw  = (ushort_t*)(ws);
  ushort_t* Qw  = (ushort_t*)(ws + 2359296);
  ushort_t* Kw  = (ushort_t*)(ws + 10747904);
  ushort_t* UT  = (ushort_t*)(ws + 19136512);
  __hip_bfloat16* Ow = (__hip_bfloat16*)(ws + 69468160);
  ushort_t* Xw  = (ushort_t*)(ws + 69468160);   // aliases Ow (dead until attn)
  ushort_t* Wqw = (ushort_t*)(ws + 75759616);   // aliases Ow
  ushort_t* Wkw = (ushort_t*)(ws + 76054528);   // aliases Ow

  // zero the dq 48->64 pad of Q/K (contiguous Qw+Kw region)
  hipMemsetAsync(ws + 2359296, 0, 16777216, stream);

  cvt_kernel<<<dim3(3072), 256, 0, stream>>>(X, Xw, 786432);
  cvt_kernel<<<dim3(144), 256, 0, stream>>>(Wq, Wqw, 36864);
  cvt_kernel<<<dim3(144), 256, 0, stream>>>(Wk, Wkw, 36864);
  prep_m_kernel<<<dim3(6, 6, 8), 256, 0, stream>>>(Wr, Wv, Mw);

  gemm_kernel<0><<<dim3(64, 3), 256, 0, stream>>>(Xw, Wqw, Qw);
  gemm_kernel<0><<<dim3(64, 3), 256, 0, stream>>>(Xw, Wkw, Kw);
  gemm_kernel<1><<<dim3(3, 16, 32), 256, 0, stream>>>(Mw, Xw, UT);

  attn_pv_kernel<<<dim3(1024), 256, 0, stream>>>(Qw, Kw, UT, (__hip_bfloat16*)Ow);
  reduce_kernel<<<dim3(6144), 256, 0, stream>>>((const uint_t*)Ow, (float2*)d_out);
}

// Round 4
// 386.613 us; speedup vs baseline: 15.3350x; 1.0161x over previous
//
#include <hip/hip_runtime.h>
#include <hip/hip_bf16.h>

// B=4, N=2048, DIMX=384, DIMQ=48, H=8.
// out_b = sum_h softmax(Q K^T/sqrt(48)) @ U_bh,  U_bh = X_b M_h^T,  M_h = W_rh W_vh.
// ws layout (bytes), with Xw/Wqw/Wkw aliased INSIDE Ow (dead until attn runs):
//   Mw  bf16 [h*384+c][k:384]          @ 0           (2,359,296)
//   Qw  bf16 [bh][i:2048][d:64 pad]    @ 2,359,296   (8,388,608)
//   Kw  bf16 same                      @ 10,747,904  (8,388,608)
//   UT  bf16 [bh][c:384][j:2048]       @ 19,136,512  (50,331,648)
//   Ow  bf16 [bh][i:2048][c:384]       @ 69,468,160  (50,331,648)
//     Xw  bf16 [b][j:2048][k:384]      @ 69,468,160  (6,291,456)   } alias Ow
//     Wqw bf16 [384][384]              @ 75,759,616  (294,912)     }
//     Wkw bf16 [384][384]              @ 76,054,528  (294,912)     }
// peak = 119,799,808 B

typedef short bf16x8 __attribute__((ext_vector_type(8)));
typedef float f32x4 __attribute__((ext_vector_type(4)));
typedef unsigned short ushort_t;
typedef unsigned int uint_t;

#define MFMA16(A, B, C) __builtin_amdgcn_mfma_f32_16x16x32_bf16(A, B, C, 0, 0, 0)

__device__ __forceinline__ ushort_t bits_bf16(float a) {
  __hip_bfloat16 h = __float2bfloat16(a);
  return *reinterpret_cast<ushort_t*>(&h);
}

// ---------- fp32 -> bf16 convert ----------
__global__ __launch_bounds__(256) void cvt_kernel(const float* __restrict__ src,
                                                  ushort_t* __restrict__ dst, int n4) {
  const int idx = blockIdx.x * 256 + threadIdx.x;
  if (idx >= n4) return;
  const float4 v = ((const float4*)src)[idx];
  ushort4 o;
  o.x = bits_bf16(v.x); o.y = bits_bf16(v.y); o.z = bits_bf16(v.z); o.w = bits_bf16(v.w);
  ((ushort4*)dst)[idx] = o;
}

// ---------- M_h = W_rh * W_vh  (fp32 compute, bf16 out; tiny) ----------
__global__ __launch_bounds__(256) void prep_m_kernel(const float* __restrict__ Wr,
                                                     const float* __restrict__ Wv,
                                                     ushort_t* __restrict__ Mw) {
  __shared__ float As[32][68];
  __shared__ float Bs[32][68];
  const int t = threadIdx.x;
  const int d0 = blockIdx.x << 6;
  const int k0 = blockIdx.y << 6;
  const int h  = blockIdx.z;
  const int ty = t >> 4, tx = t & 15;
  float acc[4][4] = {};
  for (int x0 = 0; x0 < 384; x0 += 32) {
#pragma unroll
    for (int rep = 0; rep < 2; ++rep) {
      int idx = t + (rep << 8);
      int row = idx >> 3, kq = (idx & 7) << 2;
      const float4 a = *(const float4*)&Wr[(size_t)(d0 + row) * 3072 + h * 384 + x0 + kq];
      As[kq + 0][row] = a.x; As[kq + 1][row] = a.y; As[kq + 2][row] = a.z; As[kq + 3][row] = a.w;
      int bro = idx >> 4, bc4 = (idx & 15) << 2;
      *(float4*)&Bs[bro][bc4] = *(const float4*)&Wv[(size_t)(h * 384 + x0 + bro) * 384 + k0 + bc4];
    }
    __syncthreads();
#pragma unroll
    for (int kk = 0; kk < 32; ++kk) {
      const float4 av = *(const float4*)&As[kk][ty << 2];
      const float4 bv = *(const float4*)&Bs[kk][tx << 2];
      const float a[4] = {av.x, av.y, av.z, av.w};
      const float b[4] = {bv.x, bv.y, bv.z, bv.w};
#pragma unroll
      for (int r = 0; r < 4; ++r)
#pragma unroll
        for (int c = 0; c < 4; ++c) acc[r][c] = fmaf(a[r], b[c], acc[r][c]);
    }
    __syncthreads();
  }
#pragma unroll
  for (int r = 0; r < 4; ++r)
#pragma unroll
    for (int c = 0; c < 4; ++c)
      Mw[(size_t)(h * 384 + d0 + (ty << 2) + r) * 384 + k0 + (tx << 2) + c] =
          bits_bf16(acc[r][c]);
}

// ---------- unified bf16 MFMA GEMM (unchanged from round 3) ----------
template <int MODE>
__global__ __launch_bounds__(256) void gemm_kernel(const ushort_t* __restrict__ Aall,
                                                   const ushort_t* __restrict__ Ball,
                                                   ushort_t* __restrict__ dst) {
  __shared__ ushort_t As[128 * 40];
  __shared__ ushort_t Bs[128 * 40];
  const int t = threadIdx.x;
  const int w = t >> 6, lane = t & 63, quad = lane >> 4, l16 = lane & 15;
  const int m0 = blockIdx.x << 7;
  const int n0 = blockIdx.y << 7;
  const ushort_t* Ap;
  const ushort_t* Bp;
  if (MODE == 0) {
    Ap = Aall; Bp = Ball;
  } else {
    const int bh = blockIdx.z, h = bh & 7, b = bh >> 3;
    Ap = Aall + (size_t)h * 384 * 384;
    Bp = Ball + (size_t)b * 2048 * 384;
  }
  const int wm = (w & 1) << 6, wn = (w >> 1) << 6;
  f32x4 acc[4][4] = {};

  for (int k0 = 0; k0 < 384; k0 += 32) {
    __syncthreads();
#pragma unroll
    for (int rep = 0; rep < 2; ++rep) {
      const int idx = t + (rep << 8);
      const int row = idx >> 2, c8 = (idx & 3) << 3;
      *(bf16x8*)&As[row * 40 + c8] = *(const bf16x8*)&Ap[(size_t)(m0 + row) * 384 + k0 + c8];
      *(bf16x8*)&Bs[row * 40 + c8] = *(const bf16x8*)&Bp[(size_t)(n0 + row) * 384 + k0 + c8];
    }
    __syncthreads();
    bf16x8 af[4], bfr[4];
#pragma unroll
    for (int x = 0; x < 4; ++x) {
      af[x] = *(const bf16x8*)&As[(wm + x * 16 + l16) * 40 + quad * 8];
      bfr[x] = *(const bf16x8*)&Bs[(wn + x * 16 + l16) * 40 + quad * 8];
    }
#pragma unroll
    for (int ti = 0; ti < 4; ++ti)
#pragma unroll
      for (int tj = 0; tj < 4; ++tj)
        acc[ti][tj] = MFMA16(af[ti], bfr[tj], acc[ti][tj]);
  }

#pragma unroll
  for (int ti = 0; ti < 4; ++ti) {
    const int gm0 = m0 + wm + ti * 16 + quad * 4;
#pragma unroll
    for (int tj = 0; tj < 4; ++tj) {
      const int gn = n0 + wn + tj * 16 + l16;
#pragma unroll
      for (int r = 0; r < 4; ++r) {
        const ushort_t v = bits_bf16(acc[ti][tj][r]);
        if (MODE == 0) {
          const int m = gm0 + r, b = m >> 11, i = m & 2047;
          const int h = gn / 48, dd = gn - h * 48;
          dst[(size_t)(((b << 3) + h) * 2048 + i) * 64 + dd] = v;
        } else {
          dst[((size_t)blockIdx.z * 384 + gm0 + r) * 2048 + gn] = v;
        }
      }
    }
  }
}

// ---------- fused attention via MFMA, round-4 pipeline ----------
// 1 barrier/jt (double-buffered Ps, stride 44 words = 2-way-max banks).
// U fragments issued at TOP of jt: the barrier's vmcnt(0) drain doubles as their wait,
// so PV runs on register-resident U with no vmem stall.
__global__ __launch_bounds__(256, 2) void attn_pv_kernel(const ushort_t* __restrict__ Qw,
                                                         const ushort_t* __restrict__ Kw,
                                                         const ushort_t* __restrict__ UT,
                                                         __hip_bfloat16* __restrict__ Ow) {
  __shared__ uint_t Ps[2][64 * 44];
  __shared__ float Lw[4][64];
  __shared__ float Ls[64];

  const int t = threadIdx.x;
  const int w = t >> 6, lane = t & 63, quad = lane >> 4, l16 = lane & 15;
  const int bid = blockIdx.x;
  const int h = bid & 7, i0 = ((bid >> 3) & 31) << 6, b = bid >> 8;
  const int bh = (b << 3) + h;

  const ushort_t* Qg = Qw + ((size_t)bh * 2048 + i0 + l16) * 64 + quad * 8;
  const ushort_t* Kg = Kw + ((size_t)bh * 2048 + w * 16 + l16) * 64 + quad * 8;
  const ushort_t* Ug = UT + ((size_t)bh * 384 + w * 96 + l16) * 2048 + quad * 8;

  bf16x8 qf[4][2];
#pragma unroll
  for (int ti = 0; ti < 4; ++ti)
#pragma unroll
    for (int kh = 0; kh < 2; ++kh)
      qf[ti][kh] = *(const bf16x8*)(Qg + (size_t)ti * 16 * 64 + kh * 32);

  f32x4 acc[4][6] = {};
  float lp[4] = {0.f, 0.f, 0.f, 0.f};
  // exp(s/sqrt(48)) = exp2(s * log2(e)/sqrt(48))
  const float c_exp = 0.14433756729740643f * 1.4426950408889634f;

  bf16x8 kf0 = *(const bf16x8*)(Kg);
  bf16x8 kf1 = *(const bf16x8*)(Kg + 32);
  int buf = 0;

  for (int jt = 0; jt < 32; ++jt) {
    const int j0 = jt << 6;
    // ---- issue U(jt) fragment loads first: long flight, waited at the barrier ----
    bf16x8 uf[6][2];
#pragma unroll
    for (int tc = 0; tc < 6; ++tc) {
      const ushort_t* up = Ug + (size_t)tc * 16 * 2048 + j0;
      uf[tc][0] = *(const bf16x8*)(up);
      uf[tc][1] = *(const bf16x8*)(up + 32);
    }
    // ---- scores: S^T tile, wave w owns j-strip w*16..+15 ----
    f32x4 sv[4];
#pragma unroll
    for (int ti = 0; ti < 4; ++ti) {
      f32x4 z = {0.f, 0.f, 0.f, 0.f};
      z = MFMA16(kf0, qf[ti][0], z);
      z = MFMA16(kf1, qf[ti][1], z);
      sv[ti] = z;
    }
    // ---- prefetch next K tile ----
    const int jn = ((jt + 1) & 31) << 6;
    bf16x8 kn0 = *(const bf16x8*)(Kg + (size_t)jn * 64);
    bf16x8 kn1 = *(const bf16x8*)(Kg + (size_t)jn * 64 + 32);
    // ---- exp via exp2 + round-to-bf16 (bits+0x8000) + v_perm pack ----
    uint_t pw[4][2];
#pragma unroll
    for (int ti = 0; ti < 4; ++ti) {
      const uint_t r0 = __float_as_uint(exp2f(sv[ti][0] * c_exp)) + 0x8000u;
      const uint_t r1 = __float_as_uint(exp2f(sv[ti][1] * c_exp)) + 0x8000u;
      const uint_t r2 = __float_as_uint(exp2f(sv[ti][2] * c_exp)) + 0x8000u;
      const uint_t r3 = __float_as_uint(exp2f(sv[ti][3] * c_exp)) + 0x8000u;
      const uint_t p0 = __builtin_amdgcn_perm(r1, r0, 0x07060302u);  // [e1_hi|e0_hi]
      const uint_t p1 = __builtin_amdgcn_perm(r3, r2, 0x07060302u);
      pw[ti][0] = p0;
      pw[ti][1] = p1;
      // l from the STORED (rounded) values so normalization is exact
      lp[ti] += (__uint_as_float(p0 << 16) + __uint_as_float(p0 & 0xffff0000u)) +
                (__uint_as_float(p1 << 16) + __uint_as_float(p1 & 0xffff0000u));
    }
    // ---- write Ps[buf] (b64, 2-way max banks at stride 44) ----
    {
      uint2* p = (uint2*)&Ps[buf][w * 8 + quad * 2];
#pragma unroll
      for (int ti = 0; ti < 4; ++ti)
        *(uint2*)((uint_t*)p + (ti * 16 + l16) * 44) = uint2{pw[ti][0], pw[ti][1]};
    }
    __syncthreads();  // single barrier: Ps ready + drains U/K loads (issued ~500cyc ago)
    // ---- P A-fragments: ds_read_b128, 2-way banks ----
    bf16x8 pA[4][2];
#pragma unroll
    for (int ti = 0; ti < 4; ++ti)
#pragma unroll
      for (int ks = 0; ks < 2; ++ks)
        pA[ti][ks] = *(const bf16x8*)&Ps[buf][(ti * 16 + l16) * 44 + ks * 16 + quad * 4];
    // ---- PV: all operands register-resident ----
#pragma unroll
    for (int tc = 0; tc < 6; ++tc) {
#pragma unroll
      for (int ti = 0; ti < 4; ++ti) acc[ti][tc] = MFMA16(pA[ti][0], uf[tc][0], acc[ti][tc]);
#pragma unroll
      for (int ti = 0; ti < 4; ++ti) acc[ti][tc] = MFMA16(pA[ti][1], uf[tc][1], acc[ti][tc]);
    }
    kf0 = kn0;
    kf1 = kn1;
    buf ^= 1;
  }

  // ---- softmax denominators ----
#pragma unroll
  for (int ti = 0; ti < 4; ++ti) {
    lp[ti] += __shfl_xor(lp[ti], 16);
    lp[ti] += __shfl_xor(lp[ti], 32);
  }
  if (lane < 16) {
#pragma unroll
    for (int ti = 0; ti < 4; ++ti) Lw[w][ti * 16 + lane] = lp[ti];
  }
  __syncthreads();
  if (t < 64) Ls[t] = 1.0f / (Lw[0][t] + Lw[1][t] + Lw[2][t] + Lw[3][t]);
  __syncthreads();

  // ---- epilogue: normalize, store bf16 partial O ----
  __hip_bfloat16* Op = Ow + ((size_t)bh * 2048 + i0) * 384 + w * 96 + l16;
#pragma unroll
  for (int ti = 0; ti < 4; ++ti)
#pragma unroll
    for (int r = 0; r < 4; ++r) {
      const float inv = Ls[ti * 16 + quad * 4 + r];
      __hip_bfloat16* op = Op + (size_t)(ti * 16 + quad * 4 + r) * 384;
#pragma unroll
      for (int tc = 0; tc < 6; ++tc) op[tc * 16] = __float2bfloat16(acc[ti][tc][r] * inv);
    }
}

// ---------- reduce 8 heads ----------
__global__ __launch_bounds__(256) void reduce_kernel(const uint_t* __restrict__ OwU,
                                                     float2* __restrict__ out) {
  const int idx = blockIdx.x * 256 + threadIdx.x;
  const int b = idx / 393216;
  const int rem = idx - b * 393216;
  const uint_t* p = OwU + (size_t)b * 8 * 393216 + rem;
  float s0 = 0.f, s1 = 0.f;
#pragma unroll
  for (int h = 0; h < 8; ++h) {
    const uint_t v = p[(size_t)h * 393216];
    s0 += __uint_as_float(v << 16);
    s1 += __uint_as_float(v & 0xffff0000u);
  }
  out[(size_t)b * 393216 + rem] = float2{s0, s1};
}

extern "C" void kernel_launch(void* const* d_in, const int* in_sizes, int n_in,
                              void* d_out, int out_size, void* d_ws, size_t ws_size,
                              hipStream_t stream) {
  const float* X  = (const float*)d_in[0];
  const float* Wq = (const float*)d_in[1];
  const float* Wk = (const float*)d_in[2];
  const float* Wv = (const float*)d_in[3];
  const float* Wr = (const float*)d_in[4];

  char* ws = (char*)d_ws;
  ushort_t* Mw  = (ushort_t*)(ws);
  ushort_t* Qw  = (ushort_t*)(ws + 2359296);
  ushort_t* Kw  = (ushort_t*)(ws + 10747904);
  ushort_t* UT  = (ushort_t*)(ws + 19136512);
  __hip_bfloat16* Ow = (__hip_bfloat16*)(ws + 69468160);
  ushort_t* Xw  = (ushort_t*)(ws + 69468160);   // aliases Ow (dead until attn)
  ushort_t* Wqw = (ushort_t*)(ws + 75759616);   // aliases Ow
  ushort_t* Wkw = (ushort_t*)(ws + 76054528);   // aliases Ow

  hipMemsetAsync(ws + 2359296, 0, 16777216, stream);  // dq 48->64 pad of Q/K

  cvt_kernel<<<dim3(3072), 256, 0, stream>>>(X, Xw, 786432);
  cvt_kernel<<<dim3(144), 256, 0, stream>>>(Wq, Wqw, 36864);
  cvt_kernel<<<dim3(144), 256, 0, stream>>>(Wk, Wkw, 36864);
  prep_m_kernel<<<dim3(6, 6, 8), 256, 0, stream>>>(Wr, Wv, Mw);

  gemm_kernel<0><<<dim3(64, 3), 256, 0, stream>>>(Xw, Wqw, Qw);
  gemm_kernel<0><<<dim3(64, 3), 256, 0, stream>>>(Xw, Wkw, Kw);
  gemm_kernel<1><<<dim3(3, 16, 32), 256, 0, stream>>>(Mw, Xw, UT);

  attn_pv_kernel<<<dim3(1024), 256, 0, stream>>>(Qw, Kw, UT, Ow);
  reduce_kernel<<<dim3(6144), 256, 0, stream>>>((const uint_t*)Ow, (float2*)d_out);
}